// Round 2
// baseline (239.485 us; speedup 1.0000x reference)
//
#include <hip/hip_runtime.h>

// RNN: h_{t+1} = tanh(x_t @ W_ih^T + b_ih + b_hh + h_t @ W_hh^T), out = h_T @ fc_w^T + fc_b
// B=8192, T=512, IN=8, H=16.
//
// Mapping: 16 lanes per batch element (lane j owns hidden unit j and W_hh row j /
// W_ih row j in registers). 256-thread block = 16 batch elements. Grid = 512 blocks
// (2 blocks/CU, 8 waves/CU, 2 waves/SIMD).
// h exchange per step via per-group LDS (within-wave, in-order LDS => no barrier).
// x staged to LDS in coalesced 32-timestep tiles.

#define RNN_B   8192
#define RNN_T   512
#define RNN_IN  8
#define RNN_H   16
#define TC      32                 // timesteps per x tile
#define NB      16                 // batch elements per block
#define XSTRIDE 264                // padded floats per xs row (TC*IN=256 +8 pad -> bank-disjoint groups)
#define HP      20                 // padded floats per hbuf group

__global__ __launch_bounds__(256, 2) void rnn_fused_kernel(
    const float* __restrict__ x,     // [B, T, IN]
    const float* __restrict__ W_ih,  // [H, IN]
    const float* __restrict__ W_hh,  // [H, H]
    const float* __restrict__ b_ih,  // [H]
    const float* __restrict__ b_hh,  // [H]
    const float* __restrict__ fc_w,  // [1, H]
    const float* __restrict__ fc_b,  // [1]
    float* __restrict__ out)         // [B, 1]
{
    __shared__ float xs[NB * XSTRIDE];   // x tile: 16 rows x (32 t x 8 in), padded
    __shared__ float hbuf[NB * HP];      // h vectors, padded

    const int tid = (int)threadIdx.x;
    const int j   = tid & 15;            // hidden unit
    const int g   = tid >> 4;            // group (batch element) within block
    const int b0  = (int)blockIdx.x * NB;
    const int b   = b0 + g;

    // --- per-lane weights (row j) ---
    float whh[RNN_H];
#pragma unroll
    for (int k = 0; k < RNN_H; k += 4) {
        float4 w = *(const float4*)(W_hh + j * RNN_H + k);
        whh[k] = w.x; whh[k+1] = w.y; whh[k+2] = w.z; whh[k+3] = w.w;
    }
    float wih[RNN_IN];
#pragma unroll
    for (int i = 0; i < RNN_IN; i += 4) {
        float4 w = *(const float4*)(W_ih + j * RNN_IN + i);
        wih[i] = w.x; wih[i+1] = w.y; wih[i+2] = w.z; wih[i+3] = w.w;
    }
    const float bias = b_ih[j] + b_hh[j];

    // h0 = 0 (within-wave LDS write; group's lanes are all in this wave)
    hbuf[g * HP + j] = 0.0f;

    float hlast = 0.0f;

    for (int t0 = 0; t0 < RNN_T; t0 += TC) {
        __syncthreads();   // previous tile's xs reads complete
        // --- stage x tile: 16 rows x 256 floats = 1024 float4; 4 per thread ---
#pragma unroll
        for (int p = 0; p < 4; ++p) {
            int idx = tid + p * 256;
            int row = idx >> 6;          // 0..15
            int off = idx & 63;          // float4 index within row
            float4 v = *(const float4*)(x + ((size_t)(b0 + row) * RNN_T + t0) * RNN_IN + off * 4);
            *(float4*)(xs + row * XSTRIDE + off * 4) = v;
        }
        __syncthreads();

#pragma unroll 4
        for (int tt = 0; tt < TC; ++tt) {
            const float* xp = xs + g * XSTRIDE + tt * RNN_IN;
            const float4 xa = *(const float4*)(xp);
            const float4 xb = *(const float4*)(xp + 4);
            const float4 h0 = *(const float4*)(hbuf + g * HP + 0);
            const float4 h1 = *(const float4*)(hbuf + g * HP + 4);
            const float4 h2 = *(const float4*)(hbuf + g * HP + 8);
            const float4 h3 = *(const float4*)(hbuf + g * HP + 12);

            // 4 independent accumulator chains (dep depth ~6)
            float a0 = fmaf(wih[0], xa.x, bias);
            a0 = fmaf(wih[1], xa.y, a0);
            a0 = fmaf(wih[2], xa.z, a0);
            a0 = fmaf(wih[3], xa.w, a0);
            a0 = fmaf(whh[0], h0.x, a0);
            a0 = fmaf(whh[1], h0.y, a0);

            float a1 = wih[4] * xb.x;
            a1 = fmaf(wih[5], xb.y, a1);
            a1 = fmaf(wih[6], xb.z, a1);
            a1 = fmaf(wih[7], xb.w, a1);
            a1 = fmaf(whh[2], h0.z, a1);
            a1 = fmaf(whh[3], h0.w, a1);

            float a2 = whh[4] * h1.x;
            a2 = fmaf(whh[5],  h1.y, a2);
            a2 = fmaf(whh[6],  h1.z, a2);
            a2 = fmaf(whh[7],  h1.w, a2);
            a2 = fmaf(whh[8],  h2.x, a2);
            a2 = fmaf(whh[9],  h2.y, a2);

            float a3 = whh[10] * h2.z;
            a3 = fmaf(whh[11], h2.w, a3);
            a3 = fmaf(whh[12], h3.x, a3);
            a3 = fmaf(whh[13], h3.y, a3);
            a3 = fmaf(whh[14], h3.z, a3);
            a3 = fmaf(whh[15], h3.w, a3);

            const float s = (a0 + a1) + (a2 + a3);

            // tanh(s) = 1 - 2/(exp(2s)+1); saturates correctly at +/-inf
            const float e  = __expf(s + s);
            const float r  = __builtin_amdgcn_rcpf(e + 1.0f);
            const float hn = fmaf(-2.0f, r, 1.0f);

            hbuf[g * HP + j] = hn;   // visible to next step's reads (same wave, in-order LDS)
            hlast = hn;
        }
    }

    // --- epilogue: out[b] = sum_j fc_w[j] * h_j + fc_b ---
    float v = hlast * fc_w[j];
    v += __shfl_xor(v, 1);
    v += __shfl_xor(v, 2);
    v += __shfl_xor(v, 4);
    v += __shfl_xor(v, 8);
    if (j == 0) out[b] = v + fc_b[0];
}

extern "C" void kernel_launch(void* const* d_in, const int* in_sizes, int n_in,
                              void* d_out, int out_size, void* d_ws, size_t ws_size,
                              hipStream_t stream)
{
    const float* x    = (const float*)d_in[0];
    const float* W_ih = (const float*)d_in[1];
    const float* W_hh = (const float*)d_in[2];
    const float* b_ih = (const float*)d_in[3];
    const float* b_hh = (const float*)d_in[4];
    const float* fc_w = (const float*)d_in[5];
    const float* fc_b = (const float*)d_in[6];
    float* out = (float*)d_out;

    dim3 grid(RNN_B / NB);   // 512 blocks
    dim3 block(256);
    rnn_fused_kernel<<<grid, block, 0, stream>>>(x, W_ih, W_hh, b_ih, b_hh, fc_w, fc_b, out);
}